// Round 17
// baseline (113.222 us; speedup 1.0000x reference)
//
#include <hip/hip_runtime.h>
#include <hip/hip_bf16.h>

typedef __attribute__((ext_vector_type(8))) short bf16x8;
typedef __attribute__((ext_vector_type(4))) float f32x4;
typedef unsigned int u32;
typedef unsigned short u16;

#define XI_ROW 4128   // N + 2L
#define KP     8448   // M * W, k' = j*256 + m
#define NB     1024
#define NN     4096
#define DDIM   512

__device__ __forceinline__ u16 f2bf(float f) {
  union { float f; unsigned u; } c; c.f = f;
  return (u16)((c.u + 0x7FFFu + ((c.u >> 16) & 1u)) >> 16);
}
__device__ __forceinline__ float bf2f(u16 h) {
  union { u32 u; float f; } c; c.u = ((u32)h) << 16; return c.f;
}
__device__ __forceinline__ u32 pk2bf(float a, float b) {
  return (u32)f2bf(a) | ((u32)f2bf(b) << 16);
}
__device__ __forceinline__ void gld16(const u16* g, u16* l) {
  __builtin_amdgcn_global_load_lds(
      (const __attribute__((address_space(1))) u32*)(const void*)g,
      (__attribute__((address_space(3))) u32*)(void*)l, 16, 0, 0);
}

#define BAR() __builtin_amdgcn_s_barrier()
#define LGKM0() asm volatile("s_waitcnt lgkmcnt(0)" ::: "memory")
#define WAITVM(N) asm volatile("s_waitcnt vmcnt(" #N ")" ::: "memory")
#define SCHED0() __builtin_amdgcn_sched_barrier(0)

// ---------------------------------------------------------------------------
// Prep: convW [0,4224), convU [4224,4736).
// ---------------------------------------------------------------------------
__global__ __launch_bounds__(256) void k_prep(
    const float* __restrict__ w, const float* __restrict__ u,
    u16* __restrict__ Wbf, u16* __restrict__ Ubf) {
  const int bx = blockIdx.x, t = threadIdx.x;
  if (bx < 4224) {                       // weight f32 -> bf16, k'=j*256+m rows
    int kp = bx * 2 + (t >> 7), tl = t & 127;
    int m = kp & 255, j = kp >> 8;
    float4 v = ((const float4*)(w + (size_t)(m * 33 + j) * DDIM))[tl];
    ((uint2*)(Wbf + (size_t)kp * DDIM))[tl] =
        make_uint2(pk2bf(v.x, v.y), pk2bf(v.z, v.w));
  } else {                               // u f32 -> bf16
    int b = (bx - 4224) * 2 + (t >> 7), tl = t & 127;
    float4 v = ((const float4*)(u + (size_t)b * DDIM))[tl];
    ((uint2*)(Ubf + (size_t)b * DDIM))[tl] =
        make_uint2(pk2bf(v.x, v.y), pk2bf(v.z, v.w));
  }
}

// ---------------------------------------------------------------------------
// 2-phase pipelined core for GEMM1 (proven): 128x128 tile, 4 waves, BK=64.
// ---------------------------------------------------------------------------
template<int KSTEPS, int AS, int BS>
__device__ __forceinline__ void gemm_pipeline(
    const u16* __restrict__ aSrc, const u16* __restrict__ bSrc,
    u16* As0, u16* As1, u16* Bl0, u16* Bl1,
    int wid, int wr, int wc, int rl, int kg, int rl7,
    f32x4 (&acc)[4][4]) {

  auto stage = [&](u16* Ab, u16* Bb, int kk) {
#pragma unroll
    for (int i = 0; i < 4; ++i)
      gld16(aSrc + (size_t)i * 8 * AS + kk, &Ab[(wid * 4 + i) * 512]);
#pragma unroll
    for (int i = 0; i < 4; ++i)
      gld16(bSrc + (size_t)i * 8 * BS + kk, &Bb[(wid * 4 + i) * 512]);
  };
  auto compute = [&](const u16* Ab, const u16* Bb) {
#pragma unroll
    for (int kh = 0; kh < 2; ++kh) {
      bf16x8 af[4], bfv[4];
#pragma unroll
      for (int fm = 0; fm < 4; ++fm)
        af[fm] = *(const bf16x8*)&Ab[(wr * 64 + fm * 16 + rl) * 64 +
                                     (((kh * 4 + kg) ^ rl7) * 8)];
#pragma unroll
      for (int fn = 0; fn < 4; ++fn)
        bfv[fn] = *(const bf16x8*)&Bb[(wc * 64 + fn * 16 + rl) * 64 +
                                      (((kh * 4 + kg) ^ rl7) * 8)];
      __builtin_amdgcn_s_setprio(1);
#pragma unroll
      for (int fm = 0; fm < 4; ++fm)
#pragma unroll
        for (int fn = 0; fn < 4; ++fn)
          acc[fm][fn] = __builtin_amdgcn_mfma_f32_16x16x32_bf16(
              af[fm], bfv[fn], acc[fm][fn], 0, 0, 0);
      __builtin_amdgcn_s_setprio(0);
    }
  };

  stage(As0, Bl0, 0);
  WAITVM(0);
  BAR();
#pragma unroll 1
  for (int ts = 0; ts < KSTEPS - 2; ts += 2) {
    stage(As1, Bl1, (ts + 1) * 64);
    WAITVM(8);
    BAR();
    compute(As0, Bl0);
    BAR();
    stage(As0, Bl0, (ts + 2) * 64);
    WAITVM(8);
    BAR();
    compute(As1, Bl1);
    BAR();
  }
  stage(As1, Bl1, (KSTEPS - 1) * 64);
  WAITVM(8);
  BAR();
  compute(As0, Bl0);
  BAR();
  WAITVM(0);
  BAR();
  compute(As1, Bl1);
}

// ---------------------------------------------------------------------------
// GEMM1 (+ transpose-xi fold): blocks [0,528) GEMM; [528,1560) transpose xi.
// ---------------------------------------------------------------------------
__global__ __launch_bounds__(256) void k_gemm1(
    const u16* __restrict__ Wbf, const u16* __restrict__ Ubf,
    const float* __restrict__ Bsrc, u16* __restrict__ Gt,
    const float* __restrict__ xi, u16* __restrict__ xiT) {
  __shared__ u16 lds1[32768];            // 64 KB: staging, then Lt / tile
  const int bx = blockIdx.x, t = threadIdx.x;

  if (bx >= 528) {                       // ---- transpose-xi path ----
    u16 (*tile)[33] = (u16(*)[33])lds1;
    int id = bx - 528;
    int cblk = id % 129, mblk = id / 129;
    int c0 = cblk * 32, m0 = mblk * 32;
    int tx = t & 31, ty = t >> 5;
#pragma unroll
    for (int i = 0; i < 4; ++i)
      tile[ty + i * 8][tx] = f2bf(xi[(size_t)(m0 + ty + i * 8) * XI_ROW + c0 + tx]);
    __syncthreads();
#pragma unroll
    for (int i = 0; i < 4; ++i)
      xiT[(size_t)(c0 + ty + i * 8) * 256 + m0 + tx] = tile[tx][ty + i * 8];
    return;
  }

  u16* As0 = lds1;
  u16* As1 = lds1 + 8192;
  u16* Bl0 = lds1 + 16384;
  u16* Bl1 = lds1 + 24576;
  const int r0 = (bx % 66) * 128;
  const int b0 = (bx / 66) * 128;
  const int lane = t & 63, wid = t >> 6;
  const int wr = wid >> 1, wc = wid & 1;
  const int rl = lane & 15, kg = lane >> 4, rl7 = rl & 7;
  const int lr = lane >> 3, lc = (lane & 7) ^ (lr & 7);
  const u16* aSrc = Wbf + (size_t)(r0 + wid * 32 + lr) * DDIM + lc * 8;
  const u16* bSrc = Ubf + (size_t)(b0 + wid * 32 + lr) * DDIM + lc * 8;

  f32x4 acc[4][4] = {};
  gemm_pipeline<8, DDIM, DDIM>(aSrc, bSrc, As0, As1, Bl0, Bl1,
                               wid, wr, wc, rl, kg, rl7, acc);

  __syncthreads();                       // all waves done reading staging LDS
  u16* Lt = lds1;                        // [128][136] bf16
#pragma unroll
  for (int fm = 0; fm < 4; ++fm) {
    int kloc = wr * 64 + fm * 16 + kg * 4;
    int kbase = r0 + kloc;
    float b4[4];
#pragma unroll
    for (int r = 0; r < 4; ++r) {
      int kk = kbase + r;
      b4[r] = Bsrc[(kk & 255) * 33 + (kk >> 8)];
    }
#pragma unroll
    for (int fn = 0; fn < 4; ++fn) {
      int bloc = wc * 64 + fn * 16 + rl;
      u16 o[4];
#pragma unroll
      for (int r = 0; r < 4; ++r) {
        float x = acc[fm][fn][r] + b4[r];
        o[r] = f2bf(1.0f / (1.0f + __expf(-x)));
      }
      *(uint2*)&Lt[bloc * 136 + kloc] =
          make_uint2((u32)o[0] | ((u32)o[1] << 16),
                     (u32)o[2] | ((u32)o[3] << 16));
    }
  }
  __syncthreads();
  const int bl = t >> 4, j = t & 15;
#pragma unroll
  for (int p = 0; p < 8; ++p) {
    int bloc = p * 16 + bl;
    uint4 v = *(const uint4*)&Lt[bloc * 136 + j * 8];
    *(uint4*)(Gt + (size_t)(b0 + bloc) * KP + r0 + j * 8) = v;
  }
}

// ---------------------------------------------------------------------------
// GEMM2 (NEW GEOMETRY): tile 256(n)x128(b), BK=32, 8 waves (4Mx2N,
// wave-tile 64x64), acc 4x4 (64 VGPR) -> <=128 regs/wave -> 2 blocks/CU
// (16 waves/CU) via __launch_bounds__(512,4). LDS 48KB (A 2x16KB, B 2x8KB).
// Grid 512 = 16n x 4ks x 8b; b-tile == XCD (lid&7) so each XCD's Gt slice
// (4x540KB=2.2MB) stays L2-resident. K-split 4: 2112 = 66 BK-steps, uniform.
// Single-barrier 8-phase (2 K-tiles/iter), 3 loads/wave/K-tile:
//   ph1: rd af01,bf01(buf0) | stA(T+1,0)->b1 | BAR lgkm0 mm(0,0)
//   ph2: rd bf23            | stA(T+1,1)->b1 | BAR lgkm0 mm(0,1)
//   ph3: rd af23            | stB(T+1) ->b1  | BAR lgkm0 mm(1,0)
//   ph4: vmcnt(0) [T+1 landed] BAR mm(1,1)
//   ph5-8: same on buf1, staging T+2->buf0 (if s2), vmcnt(0) at ph8.
// Every ds_read drains (LGKM0) in its phase, >=1 barrier before its buffer
// is re-staged (WAR safe); vmcnt is per-wave (each wave waits its own 3).
// Swizzle for 32-elem rows: store chunk (l&3)^((l>>3)&3), read chunk
// kg^((rl>>1)&3) -> 2 lanes/bank (conflict-free), verified per 16-lane phase.
// ---------------------------------------------------------------------------
__global__ __launch_bounds__(512, 4) void k_gemm2(
    const u16* __restrict__ xiT, const u16* __restrict__ Gt,
    float* __restrict__ Out, u16* __restrict__ Part, int allbf) {
  __shared__ u16 lds[24576];               // 49,152 B
  const int lid = blockIdx.x;
  const int b0 = (lid & 7) * 128;          // 8 b-tiles, one per XCD
  const int ks = (lid >> 3) & 3;           // 4 K-splits, 2112 each
  const int n0 = (lid >> 5) * 256;         // 16 n-tiles
  const int kOff = ks * 2112;

  const int t = threadIdx.x, lane = t & 63, wid = t >> 6;
  const int wr = wid >> 1, wc = wid & 1;   // 4(M) x 2(N) waves
  const int rl = lane & 15, kg = lane >> 4;
  const int sq = lane >> 2;                // staging: row within 16-row group
  const int swsrc = (lane & 3) ^ ((lane >> 3) & 3);   // staged-src chunk swz
  const int rsw = (rl >> 1) & 3;           // read chunk swz

  const u16* aS = xiT + (size_t)(n0 + wid * 32 + sq) * 256 + kOff + swsrc * 8;
  const u16* bS = Gt  + (size_t)(b0 + wid * 16 + sq) * KP  + kOff + swsrc * 8;

  u16* A0 = lds;                // [256][32]
  u16* A1 = lds + 8192;
  u16* B0 = lds + 16384;        // [128][32]
  u16* B1 = lds + 20480;

  f32x4 acc[4][4] = {};
  bf16x8 af[4], bfv[4];

  auto stA = [&](int tile, int i, u16* Ab) {
    gld16(aS + (size_t)i * 16 * 256 + (size_t)tile * 32,
          Ab + (wid * 32 + i * 16) * 32);
  };
  auto stB = [&](int tile, u16* Bb) {
    gld16(bS + (size_t)tile * 32, Bb + wid * 512);
  };
  auto rdA = [&](const u16* Ab, int fm) {
    af[fm] = *(const bf16x8*)&Ab[(wr * 64 + fm * 16 + rl) * 32 +
                                 ((kg ^ rsw) << 3)];
  };
  auto rdB = [&](const u16* Bb, int fn) {
    bfv[fn] = *(const bf16x8*)&Bb[(wc * 64 + fn * 16 + rl) * 32 +
                                  ((kg ^ rsw) << 3)];
  };
  auto mm = [&](int sm, int sn) {
    __builtin_amdgcn_s_setprio(1);
#pragma unroll
    for (int i = 0; i < 2; ++i)
#pragma unroll
      for (int j = 0; j < 2; ++j)
        acc[sm * 2 + i][sn * 2 + j] = __builtin_amdgcn_mfma_f32_16x16x32_bf16(
            af[sm * 2 + i], bfv[sn * 2 + j], acc[sm * 2 + i][sn * 2 + j],
            0, 0, 0);
    __builtin_amdgcn_s_setprio(0);
  };

  auto runIter = [&](int T, bool s2) {
    // ph1: q(0,0) tile T (buf0); stage A(T+1,0)->b1
    rdA(A0, 0); rdA(A0, 1); rdB(B0, 0); rdB(B0, 1);
    stA(T + 1, 0, A1);
    SCHED0(); BAR(); LGKM0(); SCHED0(); mm(0, 0);
    // ph2: q(0,1); stage A(T+1,1)->b1
    rdB(B0, 2); rdB(B0, 3);
    stA(T + 1, 1, A1);
    SCHED0(); BAR(); LGKM0(); SCHED0(); mm(0, 1);
    // ph3: q(1,0); stage B(T+1)->b1
    rdA(A0, 2); rdA(A0, 3);
    stB(T + 1, B1);
    SCHED0(); BAR(); LGKM0(); SCHED0(); mm(1, 0);
    // ph4: q(1,1); T+1's 3 loads landed (per-wave)
    WAITVM(0);
    SCHED0(); BAR(); SCHED0(); mm(1, 1);
    // ph5: q(0,0) tile T+1 (buf1); stage A(T+2,0)->b0
    rdA(A1, 0); rdA(A1, 1); rdB(B1, 0); rdB(B1, 1);
    if (s2) stA(T + 2, 0, A0);
    SCHED0(); BAR(); LGKM0(); SCHED0(); mm(0, 0);
    // ph6
    rdB(B1, 2); rdB(B1, 3);
    if (s2) stA(T + 2, 1, A0);
    SCHED0(); BAR(); LGKM0(); SCHED0(); mm(0, 1);
    // ph7
    rdA(A1, 2); rdA(A1, 3);
    if (s2) stB(T + 2, B0);
    SCHED0(); BAR(); LGKM0(); SCHED0(); mm(1, 0);
    // ph8: T+2's loads landed (if any)
    WAITVM(0);
    SCHED0(); BAR(); SCHED0(); mm(1, 1);
  };

  // prologue: tile 0 -> buf0 (3 loads per wave)
  stA(0, 0, A0); stA(0, 1, A0); stB(0, B0);
  WAITVM(0);
  BAR();

#pragma unroll 1
  for (int it = 0; it < 32; ++it) runIter(it * 2, true);
  runIter(64, false);                      // final iter: no T+2

  // epilogue
  if (!allbf && ks == 0) {
#pragma unroll
    for (int fm = 0; fm < 4; ++fm)
#pragma unroll
      for (int fn = 0; fn < 4; ++fn) {
        int n = n0 + wr * 64 + fm * 16 + kg * 4;
        int b = b0 + wc * 64 + fn * 16 + rl;
#pragma unroll
        for (int r = 0; r < 4; ++r)
          Out[(size_t)(n + r) * NB + b] = acc[fm][fn][r];
      }
  } else {
    int slot = allbf ? ks : (ks - 1);
    u16* P = Part + (size_t)slot * (NN * NB);
#pragma unroll
    for (int fm = 0; fm < 4; ++fm)
#pragma unroll
      for (int fn = 0; fn < 4; ++fn) {
        int n = n0 + wr * 64 + fm * 16 + kg * 4;
        int b = b0 + wc * 64 + fn * 16 + rl;
#pragma unroll
        for (int r = 0; r < 4; ++r)
          P[(size_t)(n + r) * NB + b] = f2bf(acc[fm][fn][r]);
      }
  }
}

// ---------------------------------------------------------------------------
// Reduce: allbf ? Out = P0+P1+P2+P3 : Out += P0+P1+P2. 8 floats/thread.
// ---------------------------------------------------------------------------
__global__ __launch_bounds__(256) void k_reduce(float* __restrict__ Out,
                                                const u16* __restrict__ Part,
                                                int allbf) {
  size_t i8 = ((size_t)blockIdx.x * 256 + threadIdx.x) * 8;   // float index
  float a[8];
  int np;
  if (allbf) {
#pragma unroll
    for (int q = 0; q < 8; ++q) a[q] = 0.f;
    np = 4;
  } else {
    float4 x = *(const float4*)(Out + i8);
    float4 y = *(const float4*)(Out + i8 + 4);
    a[0] = x.x; a[1] = x.y; a[2] = x.z; a[3] = x.w;
    a[4] = y.x; a[5] = y.y; a[6] = y.z; a[7] = y.w;
    np = 3;
  }
  for (int p = 0; p < np; ++p) {
    uint4 v = *(const uint4*)(Part + (size_t)p * (NN * NB) + i8);
    a[0] += bf2f((u16)(v.x & 0xFFFFu)); a[1] += bf2f((u16)(v.x >> 16));
    a[2] += bf2f((u16)(v.y & 0xFFFFu)); a[3] += bf2f((u16)(v.y >> 16));
    a[4] += bf2f((u16)(v.z & 0xFFFFu)); a[5] += bf2f((u16)(v.z >> 16));
    a[6] += bf2f((u16)(v.w & 0xFFFFu)); a[7] += bf2f((u16)(v.w >> 16));
  }
  *(float4*)(Out + i8)     = make_float4(a[0], a[1], a[2], a[3]);
  *(float4*)(Out + i8 + 4) = make_float4(a[4], a[5], a[6], a[7]);
}

// ---------------------------------------------------------------------------
extern "C" void kernel_launch(void* const* d_in, const int* in_sizes, int n_in,
                              void* d_out, int out_size, void* d_ws, size_t ws_size,
                              hipStream_t stream) {
  const float* u  = (const float*)d_in[0];   // (1024, 512)
  const float* w  = (const float*)d_in[1];   // (256, 33, 512)
  const float* bs = (const float*)d_in[2];   // (256, 33, 1)
  const float* xi = (const float*)d_in[3];   // (256, 4128)
  float* out = (float*)d_out;                // (4096, 1024) f32

  u16* xiT  = (u16*)d_ws;                          //  2,113,536 B
  u16* Gt   = (u16*)((char*)d_ws + 2113536);       // 17,301,504 B -> 19,415,040
  u16* Wbf  = (u16*)((char*)d_ws + 19415040);      //  8,650,752 B (dead after gemm1)
  u16* Ubf  = (u16*)((char*)d_ws + 28065792);      //  1,048,576 B (dead after gemm1)
  // Part aliases Wbf/Ubf (gemm2 runs after gemm1).
  u16* Part = (u16*)((char*)d_ws + 19415040);
  const int allbf = (ws_size >= 52969472ull) ? 1 : 0;

  k_prep<<<4736, 256, 0, stream>>>(w, u, Wbf, Ubf);
  k_gemm1<<<1560, 256, 0, stream>>>(Wbf, Ubf, bs, Gt, xi, xiT);
  k_gemm2<<<512, 512, 0, stream>>>(xiT, Gt, out, Part, allbf);
  k_reduce<<<2048, 256, 0, stream>>>(out, Part, allbf);
}

// Round 18
// 99.517 us; speedup vs baseline: 1.1377x; 1.1377x over previous
//
#include <hip/hip_runtime.h>
#include <hip/hip_bf16.h>

typedef __attribute__((ext_vector_type(8))) short bf16x8;
typedef __attribute__((ext_vector_type(4))) float f32x4;
typedef unsigned int u32;
typedef unsigned short u16;

#define XI_ROW 4128   // N + 2L
#define KP     8448   // M * W, k' = j*256 + m
#define NB     1024
#define NN     4096
#define DDIM   512

__device__ __forceinline__ u16 f2bf(float f) {
  union { float f; unsigned u; } c; c.f = f;
  return (u16)((c.u + 0x7FFFu + ((c.u >> 16) & 1u)) >> 16);
}
__device__ __forceinline__ float bf2f(u16 h) {
  union { u32 u; float f; } c; c.u = ((u32)h) << 16; return c.f;
}
__device__ __forceinline__ u32 pk2bf(float a, float b) {
  return (u32)f2bf(a) | ((u32)f2bf(b) << 16);
}
__device__ __forceinline__ void gld16(const u16* g, u16* l) {
  __builtin_amdgcn_global_load_lds(
      (const __attribute__((address_space(1))) u32*)(const void*)g,
      (__attribute__((address_space(3))) u32*)(void*)l, 16, 0, 0);
}

#define BAR() __builtin_amdgcn_s_barrier()
#define LGKM0() asm volatile("s_waitcnt lgkmcnt(0)" ::: "memory")
#define LGKM8() asm volatile("s_waitcnt lgkmcnt(8)" ::: "memory")
#define WAITVM(N) asm volatile("s_waitcnt vmcnt(" #N ")" ::: "memory")
#define SCHED0() __builtin_amdgcn_sched_barrier(0)

// ---------------------------------------------------------------------------
// Fused prep: convW [0,4224), convU [4224,4736), transpose xi [4736,5768).
// (r12 arrangement — best measured total.)
// ---------------------------------------------------------------------------
__global__ __launch_bounds__(256) void k_prep(
    const float* __restrict__ w, const float* __restrict__ u,
    const float* __restrict__ xi, u16* __restrict__ Wbf,
    u16* __restrict__ Ubf, u16* __restrict__ xiT) {
  __shared__ u16 tile[32][33];
  const int bx = blockIdx.x, t = threadIdx.x;
  if (bx < 4224) {                       // weight f32 -> bf16, k'=j*256+m rows
    int kp = bx * 2 + (t >> 7), tl = t & 127;
    int m = kp & 255, j = kp >> 8;
    float4 v = ((const float4*)(w + (size_t)(m * 33 + j) * DDIM))[tl];
    ((uint2*)(Wbf + (size_t)kp * DDIM))[tl] =
        make_uint2(pk2bf(v.x, v.y), pk2bf(v.z, v.w));
  } else if (bx < 4736) {                // u f32 -> bf16
    int b = (bx - 4224) * 2 + (t >> 7), tl = t & 127;
    float4 v = ((const float4*)(u + (size_t)b * DDIM))[tl];
    ((uint2*)(Ubf + (size_t)b * DDIM))[tl] =
        make_uint2(pk2bf(v.x, v.y), pk2bf(v.z, v.w));
  } else {                               // xi (256x4128) -> xiT (4128x256) bf16
    int bx2 = bx - 4736;
    int cblk = bx2 % 129, mblk = bx2 / 129;
    int c0 = cblk * 32, m0 = mblk * 32;
    int tx = t & 31, ty = t >> 5;
#pragma unroll
    for (int i = 0; i < 4; ++i)
      tile[ty + i * 8][tx] = f2bf(xi[(size_t)(m0 + ty + i * 8) * XI_ROW + c0 + tx]);
    __syncthreads();
#pragma unroll
    for (int i = 0; i < 4; ++i)
      xiT[(size_t)(c0 + ty + i * 8) * 256 + m0 + tx] = tile[tx][ty + i * 8];
  }
}

// ---------------------------------------------------------------------------
// 2-phase pipelined core for GEMM1 (proven): 128x128 tile, 4 waves, BK=64.
// ---------------------------------------------------------------------------
template<int KSTEPS, int AS, int BS>
__device__ __forceinline__ void gemm_pipeline(
    const u16* __restrict__ aSrc, const u16* __restrict__ bSrc,
    u16* As0, u16* As1, u16* Bl0, u16* Bl1,
    int wid, int wr, int wc, int rl, int kg, int rl7,
    f32x4 (&acc)[4][4]) {

  auto stage = [&](u16* Ab, u16* Bb, int kk) {
#pragma unroll
    for (int i = 0; i < 4; ++i)
      gld16(aSrc + (size_t)i * 8 * AS + kk, &Ab[(wid * 4 + i) * 512]);
#pragma unroll
    for (int i = 0; i < 4; ++i)
      gld16(bSrc + (size_t)i * 8 * BS + kk, &Bb[(wid * 4 + i) * 512]);
  };
  auto compute = [&](const u16* Ab, const u16* Bb) {
#pragma unroll
    for (int kh = 0; kh < 2; ++kh) {
      bf16x8 af[4], bfv[4];
#pragma unroll
      for (int fm = 0; fm < 4; ++fm)
        af[fm] = *(const bf16x8*)&Ab[(wr * 64 + fm * 16 + rl) * 64 +
                                     (((kh * 4 + kg) ^ rl7) * 8)];
#pragma unroll
      for (int fn = 0; fn < 4; ++fn)
        bfv[fn] = *(const bf16x8*)&Bb[(wc * 64 + fn * 16 + rl) * 64 +
                                      (((kh * 4 + kg) ^ rl7) * 8)];
      __builtin_amdgcn_s_setprio(1);
#pragma unroll
      for (int fm = 0; fm < 4; ++fm)
#pragma unroll
        for (int fn = 0; fn < 4; ++fn)
          acc[fm][fn] = __builtin_amdgcn_mfma_f32_16x16x32_bf16(
              af[fm], bfv[fn], acc[fm][fn], 0, 0, 0);
      __builtin_amdgcn_s_setprio(0);
    }
  };

  stage(As0, Bl0, 0);
  WAITVM(0);
  BAR();
#pragma unroll 1
  for (int ts = 0; ts < KSTEPS - 2; ts += 2) {
    stage(As1, Bl1, (ts + 1) * 64);
    WAITVM(8);
    BAR();
    compute(As0, Bl0);
    BAR();
    stage(As0, Bl0, (ts + 2) * 64);
    WAITVM(8);
    BAR();
    compute(As1, Bl1);
    BAR();
  }
  stage(As1, Bl1, (KSTEPS - 1) * 64);
  WAITVM(8);
  BAR();
  compute(As0, Bl0);
  BAR();
  WAITVM(0);
  BAR();
  compute(As1, Bl1);
}

// ---------------------------------------------------------------------------
// GEMM1: Gt[b][k'] = sigmoid(Wbf[k',:]·Ubf[b,:] + bias[k'])
// Epilogue: LDS transpose (Lt[128][136]) -> coalesced 16B row stores.
// ---------------------------------------------------------------------------
__global__ __launch_bounds__(256) void k_gemm1(
    const u16* __restrict__ Wbf, const u16* __restrict__ Ubf,
    const float* __restrict__ Bsrc, u16* __restrict__ Gt) {
  __shared__ u16 lds1[32768];            // 64 KB: staging, then Lt
  u16* As0 = lds1;
  u16* As1 = lds1 + 8192;
  u16* Bl0 = lds1 + 16384;
  u16* Bl1 = lds1 + 24576;
  const int r0 = blockIdx.x * 128;
  const int b0 = blockIdx.y * 128;
  const int t = threadIdx.x, lane = t & 63, wid = t >> 6;
  const int wr = wid >> 1, wc = wid & 1;
  const int rl = lane & 15, kg = lane >> 4, rl7 = rl & 7;
  const int lr = lane >> 3, lc = (lane & 7) ^ (lr & 7);
  const u16* aSrc = Wbf + (size_t)(r0 + wid * 32 + lr) * DDIM + lc * 8;
  const u16* bSrc = Ubf + (size_t)(b0 + wid * 32 + lr) * DDIM + lc * 8;

  f32x4 acc[4][4] = {};
  gemm_pipeline<8, DDIM, DDIM>(aSrc, bSrc, As0, As1, Bl0, Bl1,
                               wid, wr, wc, rl, kg, rl7, acc);

  __syncthreads();                       // all waves done reading staging LDS
  u16* Lt = lds1;                        // [128][136] bf16
#pragma unroll
  for (int fm = 0; fm < 4; ++fm) {
    int kloc = wr * 64 + fm * 16 + kg * 4;
    int kbase = r0 + kloc;
    float b4[4];
#pragma unroll
    for (int r = 0; r < 4; ++r) {
      int kk = kbase + r;
      b4[r] = Bsrc[(kk & 255) * 33 + (kk >> 8)];
    }
#pragma unroll
    for (int fn = 0; fn < 4; ++fn) {
      int bloc = wc * 64 + fn * 16 + rl;
      u16 o[4];
#pragma unroll
      for (int r = 0; r < 4; ++r) {
        float x = acc[fm][fn][r] + b4[r];
        o[r] = f2bf(1.0f / (1.0f + __expf(-x)));
      }
      *(uint2*)&Lt[bloc * 136 + kloc] =
          make_uint2((u32)o[0] | ((u32)o[1] << 16),
                     (u32)o[2] | ((u32)o[3] << 16));
    }
  }
  __syncthreads();
  const int bl = t >> 4, j = t & 15;
#pragma unroll
  for (int p = 0; p < 8; ++p) {
    int bloc = p * 16 + bl;
    uint4 v = *(const uint4*)&Lt[bloc * 136 + j * 8];
    *(uint4*)(Gt + (size_t)(b0 + bloc) * KP + r0 + j * 8) = v;
  }
}

// ---------------------------------------------------------------------------
// GEMM2: 256x256 tile, 8 waves (2Mx4N, wave-tile 128x64), BK=64.
// BALANCED K-split 4: 8448/4 = 2112 = 33 steps UNIFORM (removes the r12
// {34,34,32,32} straggler tail). 33 odd -> 15 full pair-iters + one
// pair-iter with s3=false + a barrier-free single-tile tail (tile 32 in
// buf0, fully staged at iter15 ph4-7 and drained by iter15-ph8's
// WAITVM(0)+BAR; no stage follows -> no stale-slot hazard, r10 lesson).
// In-loop schedule/staging map byte-identical to the banked r12 kernel.
// ---------------------------------------------------------------------------
__global__ __launch_bounds__(512, 2) void k_gemm2(
    const u16* __restrict__ xiT, const u16* __restrict__ Gt,
    float* __restrict__ Out, u16* __restrict__ Part, int allbf) {
  __shared__ u16 lds[65536];
  const int lid = blockIdx.x;
  const int b0 = (lid & 3) * 256;          // 4 b-tiles
  const int ks = (lid >> 2) & 3;           // 4 K-splits, 2112 each
  const int n0 = (lid >> 4) * 256;         // 16 n-tiles
  const int kOff = ks * 2112;              // 33 BK-steps, uniform

  const int t = threadIdx.x, lane = t & 63, wid = t >> 6;
  const int wr = wid >> 2, wc = wid & 3;   // 2(M) x 4(N) waves
  const int rl = lane & 15, kg = lane >> 4, rl7 = rl & 7;
  const int sr = lane >> 3;                // stage: row within 8-row group
  const int sc = (lane & 7) ^ sr;          // stage: swizzled col-chunk

  const u16* aS = xiT + (size_t)(n0 + wid * 16 + sr) * 256 + kOff + sc * 8;
  const u16* bS = Gt  + (size_t)(b0 + wid * 16 + sr) * KP  + kOff + sc * 8;

  f32x4 acc[8][4] = {};
  bf16x8 af[8], b01[4], b23[4];

  auto stA = [&](int tile, int half, int buf) {
    u16* d = lds + (buf * 4 + half) * 8192 + wid * 1024;
    const u16* s = aS + (size_t)half * 32768 + (size_t)tile * 64;
    gld16(s, d);
    gld16(s + 2048, d + 512);
  };
  auto stB = [&](int tile, int half, int buf) {
    u16* d = lds + (buf * 4 + 2 + half) * 8192 + wid * 1024;
    const u16* s = bS + (size_t)half * 128 * KP + (size_t)tile * 64;
    gld16(s, d);
    gld16(s + (size_t)8 * KP, d + 512);
  };
  auto rdA = [&](int buf, int sub) {
    const u16* p = lds + (buf * 4 + wr) * 8192;
#pragma unroll
    for (int q = 0; q < 4; ++q)
#pragma unroll
      for (int kh = 0; kh < 2; ++kh)
        af[q * 2 + kh] = *(const bf16x8*)
            &p[((sub * 4 + q) * 16 + rl) * 64 + (((kh * 4 + kg) ^ rl7) * 8)];
  };
  auto rdB = [&](int buf, int sub, bf16x8 (&bq)[4]) {
    const u16* p = lds + (buf * 4 + 2 + (wc >> 1)) * 8192;
#pragma unroll
    for (int q = 0; q < 2; ++q)
#pragma unroll
      for (int kh = 0; kh < 2; ++kh)
        bq[q * 2 + kh] = *(const bf16x8*)
            &p[((wc & 1) * 64 + (sub * 2 + q) * 16 + rl) * 64 +
               (((kh * 4 + kg) ^ rl7) * 8)];
  };
  auto mm = [&](int sm, int sn, bf16x8 (&bq)[4]) {
    __builtin_amdgcn_s_setprio(1);
#pragma unroll
    for (int q = 0; q < 4; ++q)
#pragma unroll
      for (int p = 0; p < 2; ++p)
#pragma unroll
        for (int kh = 0; kh < 2; ++kh)
          acc[sm * 4 + q][sn * 2 + p] = __builtin_amdgcn_mfma_f32_16x16x32_bf16(
              af[q * 2 + kh], bq[p * 2 + kh], acc[sm * 4 + q][sn * 2 + p], 0, 0, 0);
    __builtin_amdgcn_s_setprio(0);
  };

  // s2: T+2 valid (stages ph4-7); s3: T+3 valid (stage ph8)
  auto runIter = [&](int T, bool s2, bool s3) {
    // ph1: quad(0,0) tile T (buf0) — 12 ds_reads
    rdA(0, 0); rdB(0, 0, b01); stB(T + 1, 1, 1);
    LGKM8(); SCHED0(); BAR(); LGKM0(); SCHED0(); mm(0, 0, b01);
    // ph2: quad(0,1)
    rdB(0, 1, b23); stA(T + 1, 0, 1);
    SCHED0(); BAR(); LGKM0(); SCHED0(); mm(0, 1, b23);
    // ph3: quad(1,0)
    rdA(0, 1); stA(T + 1, 1, 1);
    SCHED0(); BAR(); LGKM0(); SCHED0(); mm(1, 0, b01);
    // ph4: quad(1,1) [no ds_reads]
    if (s2) { stB(T + 2, 0, 0); WAITVM(2); } else { WAITVM(0); }
    SCHED0(); BAR(); SCHED0(); mm(1, 1, b23);
    // ph5: quad(0,0) tile T+1 (buf1) — 12 ds_reads
    rdA(1, 0); rdB(1, 0, b01); if (s2) stB(T + 2, 1, 0);
    LGKM8(); SCHED0(); BAR(); LGKM0(); SCHED0(); mm(0, 0, b01);
    // ph6: quad(0,1)
    rdB(1, 1, b23); if (s2) stA(T + 2, 0, 0);
    SCHED0(); BAR(); LGKM0(); SCHED0(); mm(0, 1, b23);
    // ph7: quad(1,0)
    rdA(1, 1); if (s2) stA(T + 2, 1, 0);
    SCHED0(); BAR(); LGKM0(); SCHED0(); mm(1, 0, b01);
    // ph8: quad(1,1) — buf0 drained for next reads
    if (s3) { stB(T + 3, 0, 1); WAITVM(2); }
    else if (s2) { WAITVM(0); }
    SCHED0(); BAR(); SCHED0(); mm(1, 1, b23);
  };

  // prologue: T0 complete (buf0, 8 loads) + T1's B-h0 (2 loads).
  stA(0, 0, 0); stA(0, 1, 0); stB(0, 0, 0); stB(0, 1, 0);
  stB(1, 0, 1);
  WAITVM(2);
  BAR();

  // nt = 33: 15 full pair-iters, 1 pair-iter w/o s3 (no T+3=33), then tail.
#pragma unroll 1
  for (int it = 0; it < 15; ++it) runIter(it * 2, true, true);
  runIter(30, true, false);

  // tail: tile 32 in buf0 — fully landed (iter15 ph8 did WAITVM(0)+BAR).
  // No stages follow; barrier-free, register deps serialized by compiler.
  rdA(0, 0); rdB(0, 0, b01); rdB(0, 1, b23);
  mm(0, 0, b01); mm(0, 1, b23);
  rdA(0, 1);
  mm(1, 0, b01); mm(1, 1, b23);

  // epilogue
  if (!allbf && ks == 0) {
#pragma unroll
    for (int fm = 0; fm < 8; ++fm)
#pragma unroll
      for (int fn = 0; fn < 4; ++fn) {
        int n = n0 + wr * 128 + fm * 16 + kg * 4;
        int b = b0 + wc * 64 + fn * 16 + rl;
#pragma unroll
        for (int r = 0; r < 4; ++r)
          Out[(size_t)(n + r) * NB + b] = acc[fm][fn][r];
      }
  } else {
    int slot = allbf ? ks : (ks - 1);
    u16* P = Part + (size_t)slot * (NN * NB);
#pragma unroll
    for (int fm = 0; fm < 8; ++fm)
#pragma unroll
      for (int fn = 0; fn < 4; ++fn) {
        int n = n0 + wr * 128 + fm * 16 + kg * 4;
        int b = b0 + wc * 64 + fn * 16 + rl;
#pragma unroll
        for (int r = 0; r < 4; ++r)
          P[(size_t)(n + r) * NB + b] = f2bf(acc[fm][fn][r]);
      }
  }
}

// ---------------------------------------------------------------------------
// Reduce: allbf ? Out = P0+P1+P2+P3 : Out += P0+P1+P2. 8 floats/thread.
// ---------------------------------------------------------------------------
__global__ __launch_bounds__(256) void k_reduce(float* __restrict__ Out,
                                                const u16* __restrict__ Part,
                                                int allbf) {
  size_t i8 = ((size_t)blockIdx.x * 256 + threadIdx.x) * 8;   // float index
  float a[8];
  int np;
  if (allbf) {
#pragma unroll
    for (int q = 0; q < 8; ++q) a[q] = 0.f;
    np = 4;
  } else {
    float4 x = *(const float4*)(Out + i8);
    float4 y = *(const float4*)(Out + i8 + 4);
    a[0] = x.x; a[1] = x.y; a[2] = x.z; a[3] = x.w;
    a[4] = y.x; a[5] = y.y; a[6] = y.z; a[7] = y.w;
    np = 3;
  }
  for (int p = 0; p < np; ++p) {
    uint4 v = *(const uint4*)(Part + (size_t)p * (NN * NB) + i8);
    a[0] += bf2f((u16)(v.x & 0xFFFFu)); a[1] += bf2f((u16)(v.x >> 16));
    a[2] += bf2f((u16)(v.y & 0xFFFFu)); a[3] += bf2f((u16)(v.y >> 16));
    a[4] += bf2f((u16)(v.z & 0xFFFFu)); a[5] += bf2f((u16)(v.z >> 16));
    a[6] += bf2f((u16)(v.w & 0xFFFFu)); a[7] += bf2f((u16)(v.w >> 16));
  }
  *(float4*)(Out + i8)     = make_float4(a[0], a[1], a[2], a[3]);
  *(float4*)(Out + i8 + 4) = make_float4(a[4], a[5], a[6], a[7]);
}

// ---------------------------------------------------------------------------
extern "C" void kernel_launch(void* const* d_in, const int* in_sizes, int n_in,
                              void* d_out, int out_size, void* d_ws, size_t ws_size,
                              hipStream_t stream) {
  const float* u  = (const float*)d_in[0];   // (1024, 512)
  const float* w  = (const float*)d_in[1];   // (256, 33, 512)
  const float* bs = (const float*)d_in[2];   // (256, 33, 1)
  const float* xi = (const float*)d_in[3];   // (256, 4128)
  float* out = (float*)d_out;                // (4096, 1024) f32

  u16* xiT  = (u16*)d_ws;                          //  2,113,536 B
  u16* Gt   = (u16*)((char*)d_ws + 2113536);       // 17,301,504 B -> 19,415,040
  u16* Wbf  = (u16*)((char*)d_ws + 19415040);      //  8,650,752 B (dead after gemm1)
  u16* Ubf  = (u16*)((char*)d_ws + 28065792);      //  1,048,576 B (dead after gemm1)
  // Part aliases Wbf/Ubf (gemm2 runs after gemm1).
  u16* Part = (u16*)((char*)d_ws + 19415040);
  const int allbf = (ws_size >= 52969472ull) ? 1 : 0;

  k_prep<<<5768, 256, 0, stream>>>(w, u, xi, Wbf, Ubf, xiT);
  k_gemm1<<<dim3(66, 8), 256, 0, stream>>>(Wbf, Ubf, bs, Gt);
  k_gemm2<<<256, 512, 0, stream>>>(xiT, Gt, out, Part, allbf);
  k_reduce<<<2048, 256, 0, stream>>>(out, Part, allbf);
}